// Round 1
// baseline (112.390 us; speedup 1.0000x reference)
//
#include <hip/hip_runtime.h>

#define EPSILON 5.0f

constexpr int D = 512;            // feature dim
constexpr int BLOCKS = 2048;      // 8 blocks/CU on 256 CUs
constexpr int THREADS = 256;      // 4 waves/block

// Stage 1: one wave per row. dist = ||features[row] - means[labels[row]]||_2,
// hinge = max(EPSILON - dist, 0). Per-block partial sums -> d_ws.
__global__ __launch_bounds__(THREADS) void ncl_partial_kernel(
    const float* __restrict__ features,
    const float* __restrict__ means,
    const int* __restrict__ labels,
    float* __restrict__ partials,
    int B)
{
    const int lane  = threadIdx.x & 63;
    const int wave  = threadIdx.x >> 6;              // 0..3
    const int wavesPerBlock = THREADS >> 6;          // 4
    const int globalWave = blockIdx.x * wavesPerBlock + wave;
    const int totalWaves = gridDim.x * wavesPerBlock;

    float wsum = 0.0f;  // meaningful on lane 0 only

    for (int row = globalWave; row < B; row += totalWaves) {
        const int cls = labels[row];                 // wave-uniform -> scalar load
        const float4* f = reinterpret_cast<const float4*>(features + (size_t)row * D);
        const float4* m = reinterpret_cast<const float4*>(means    + (size_t)cls * D);

        float acc = 0.0f;
        #pragma unroll
        for (int k = 0; k < 2; ++k) {
            const float4 fv = f[lane + 64 * k];      // coalesced 1KiB / wave / load
            const float4 mv = m[lane + 64 * k];      // L2-resident (means = 2MiB)
            const float dx = fv.x - mv.x;
            const float dy = fv.y - mv.y;
            const float dz = fv.z - mv.z;
            const float dw = fv.w - mv.w;
            acc = fmaf(dx, dx, fmaf(dy, dy, fmaf(dz, dz, fmaf(dw, dw, acc))));
        }

        // 64-lane butterfly reduction
        #pragma unroll
        for (int off = 32; off > 0; off >>= 1)
            acc += __shfl_xor(acc, off, 64);

        if (lane == 0) {
            const float dist = sqrtf(acc);
            wsum += fmaxf(EPSILON - dist, 0.0f);
        }
    }

    __shared__ float s[4];
    if (lane == 0) s[wave] = wsum;
    __syncthreads();
    if (threadIdx.x == 0) {
        float t = 0.0f;
        #pragma unroll
        for (int i = 0; i < wavesPerBlock; ++i) t += s[i];
        partials[blockIdx.x] = t;
    }
}

// Stage 2: single block reduces BLOCKS partials, writes mean.
__global__ __launch_bounds__(THREADS) void ncl_final_kernel(
    const float* __restrict__ partials,
    int n,
    float* __restrict__ out,
    float invB)
{
    float t = 0.0f;
    for (int i = threadIdx.x; i < n; i += THREADS) t += partials[i];

    #pragma unroll
    for (int off = 32; off > 0; off >>= 1)
        t += __shfl_xor(t, off, 64);

    __shared__ float s[4];
    const int lane = threadIdx.x & 63;
    const int wave = threadIdx.x >> 6;
    if (lane == 0) s[wave] = t;
    __syncthreads();
    if (threadIdx.x == 0) {
        out[0] = (s[0] + s[1] + s[2] + s[3]) * invB;
    }
}

extern "C" void kernel_launch(void* const* d_in, const int* in_sizes, int n_in,
                              void* d_out, int out_size, void* d_ws, size_t ws_size,
                              hipStream_t stream) {
    const float* features = (const float*)d_in[0];
    const float* means    = (const float*)d_in[1];
    const int*   labels   = (const int*)d_in[2];
    float* out = (float*)d_out;

    const int B = in_sizes[2];        // one label per row
    float* partials = (float*)d_ws;   // BLOCKS floats

    ncl_partial_kernel<<<BLOCKS, THREADS, 0, stream>>>(features, means, labels,
                                                       partials, B);
    ncl_final_kernel<<<1, THREADS, 0, stream>>>(partials, BLOCKS, out,
                                                1.0f / (float)B);
}